// Round 2
// 593.666 us; speedup vs baseline: 1.1193x; 1.1193x over previous
//
#include <hip/hip_runtime.h>

#define M_DIM 1024
#define N_DIM 100000
#define K_DIM 64
#define HIST 50

#define BM 64
#define BN 128
#define NBLK_M (M_DIM / BM)             // 16
#define NBLK_N ((N_DIM + BN - 1) / BN)  // 782
#define NWG (NBLK_M * NBLK_N)           // 12512
#define WG_PER_XCD (NWG / 8)            // 1564 (exact)

typedef __attribute__((ext_vector_type(8))) short bfrag_t;   // 8 bf16 (4 VGPRs)
typedef __attribute__((ext_vector_type(16))) float accv_t;   // 16 f32 accum

// fp32 -> bf16 bits, round-to-nearest-even
__device__ __forceinline__ unsigned short f2bf(float f) {
    const unsigned u = __float_as_uint(f);
    return (unsigned short)((u + 0x7FFFu + ((u >> 16) & 1u)) >> 16);
}

// Split-bf16 MFMA GEMM + sum(s^2).
// Block: 256 threads = 4 waves, tile 64 rows x 128 items, full K=64.
// Wave (wr,wc) owns a 32x64 sub-tile = 2x mfma_f32_32x32x16_bf16 chains.
// fp32 accuracy via a_hi*b_hi + a_hi*b_lo + a_lo*b_hi (3 MFMA terms).
// B tile staged in LDS as bf16 hi/lo, row-major [128][64] with XOR swizzle
// (byte ^= (row&7)<<4) -> conflict-free b128 reads and writes.
// A fragments loaded straight from global (user rows are L2-hot).
__global__ __launch_bounds__(256, 4) void gemm_loss_kernel(
    const float* __restrict__ user_emb, const float* __restrict__ item_emb,
    const int* __restrict__ center_uid, float* __restrict__ out)
{
    __shared__ __align__(16) unsigned char ldsHi[BN * 128];  // 16 KiB
    __shared__ __align__(16) unsigned char ldsLo[BN * 128];  // 16 KiB
    __shared__ float red[4];

    const int tid = threadIdx.x;

    // XCD-aware bijective swizzle: all 16 row-tiles of an item tile land on
    // the same XCD, consecutive in time (item L2 footprint ~3.1 MB < 4 MiB).
    const int bid   = blockIdx.x;
    const int idx   = (bid & 7) * WG_PER_XCD + (bid >> 3);
    const int itile = idx >> 4;   // 0..781
    const int mtile = idx & 15;   // 0..15
    const int bm0 = mtile * BM;
    const int bi0 = itile * BN;

    // ---- stage B (item tile) as bf16 hi/lo: thread t -> row t>>1, half t&1
    // Global: 2 threads/row over 32 contiguous fp32 each (coalesced).
    // LDS: 4x b128 writes per array, swizzled (uniform bank-slot spread).
    {
        const int r  = tid >> 1;
        const int h  = tid & 1;
        const int gi = bi0 + r;
        float4 v[8];
        if (gi < N_DIM) {
            const float* src = item_emb + (size_t)gi * K_DIM + h * 32;
            #pragma unroll
            for (int s = 0; s < 8; ++s)
                v[s] = *reinterpret_cast<const float4*>(src + s * 4);
        } else {
            #pragma unroll
            for (int s = 0; s < 8; ++s) v[s] = make_float4(0.f, 0.f, 0.f, 0.f);
        }
        #pragma unroll
        for (int s = 0; s < 4; ++s) {
            const float f[8] = {v[2*s].x,   v[2*s].y,   v[2*s].z,   v[2*s].w,
                                v[2*s+1].x, v[2*s+1].y, v[2*s+1].z, v[2*s+1].w};
            bfrag_t hv, lv;
            #pragma unroll
            for (int j = 0; j < 8; ++j) {
                const unsigned short hb = f2bf(f[j]);
                const float hf = __uint_as_float((unsigned)hb << 16);
                hv[j] = (short)hb;
                lv[j] = (short)f2bf(f[j] - hf);
            }
            int addr = r * 128 + h * 64 + s * 16;
            addr ^= (r & 7) << 4;
            *reinterpret_cast<bfrag_t*>(ldsHi + addr) = hv;
            *reinterpret_cast<bfrag_t*>(ldsLo + addr) = lv;
        }
    }

    const int lane = tid & 63;
    const int wid  = tid >> 6;
    const int wr   = wid >> 1;     // row sub-block (32 rows)
    const int wc   = wid & 1;      // col sub-block (64 cols)
    const int lr   = lane & 31;
    const int lg   = lane >> 5;    // k-group (0/1)

    // A gather bases (issued before barrier; user rows are L2-resident)
    const int arow = bm0 + 32 * wr + lr;
    const int uid  = center_uid[arow];
    const float* aptr = user_emb + (size_t)uid * K_DIM + lg * 8;

    __syncthreads();

    accv_t acc0, acc1;
    #pragma unroll
    for (int i = 0; i < 16; ++i) { acc0[i] = 0.f; acc1[i] = 0.f; }

    const int rr0 = 64 * wc + lr;        // B LDS row, tile 0
    const int rr1 = rr0 + 32;            // tile 1

    #pragma unroll
    for (int ks = 0; ks < 4; ++ks) {     // K = 4 x 16
        // ---- A fragment: 8 contiguous fp32 -> bf16 hi/lo
        const float4 u0 = *reinterpret_cast<const float4*>(aptr + ks * 16);
        const float4 u1 = *reinterpret_cast<const float4*>(aptr + ks * 16 + 4);
        const float fa[8] = {u0.x, u0.y, u0.z, u0.w, u1.x, u1.y, u1.z, u1.w};
        bfrag_t ah, al;
        #pragma unroll
        for (int j = 0; j < 8; ++j) {
            const unsigned short hb = f2bf(fa[j]);
            const float hf = __uint_as_float((unsigned)hb << 16);
            ah[j] = (short)hb;
            al[j] = (short)f2bf(fa[j] - hf);
        }
        // ---- B fragments (swizzled b128 reads) + 6 MFMAs
        int b0 = rr0 * 128 + ks * 32 + (lg << 4); b0 ^= (rr0 & 7) << 4;
        int b1 = rr1 * 128 + ks * 32 + (lg << 4); b1 ^= (rr1 & 7) << 4;
        const bfrag_t bh0 = *reinterpret_cast<const bfrag_t*>(ldsHi + b0);
        const bfrag_t bl0 = *reinterpret_cast<const bfrag_t*>(ldsLo + b0);
        const bfrag_t bh1 = *reinterpret_cast<const bfrag_t*>(ldsHi + b1);
        const bfrag_t bl1 = *reinterpret_cast<const bfrag_t*>(ldsLo + b1);

        acc0 = __builtin_amdgcn_mfma_f32_32x32x16_bf16(ah, bh0, acc0, 0, 0, 0);
        acc1 = __builtin_amdgcn_mfma_f32_32x32x16_bf16(ah, bh1, acc1, 0, 0, 0);
        acc0 = __builtin_amdgcn_mfma_f32_32x32x16_bf16(ah, bl0, acc0, 0, 0, 0);
        acc1 = __builtin_amdgcn_mfma_f32_32x32x16_bf16(ah, bl1, acc1, 0, 0, 0);
        acc0 = __builtin_amdgcn_mfma_f32_32x32x16_bf16(al, bh0, acc0, 0, 0, 0);
        acc1 = __builtin_amdgcn_mfma_f32_32x32x16_bf16(al, bh1, acc1, 0, 0, 0);
    }

    // ---- epilogue: C layout col=lane&31, row=(r&3)+8*(r>>2)+4*(lane>>5).
    // Each store instr: 2 rows x 128 B contiguous (full cache lines).
    float ss = 0.f;
    float* pref = out + 1;
    const int rbase = bm0 + 32 * wr + 4 * lg;
    {
        const int col = bi0 + 64 * wc + lr;
        if (col < N_DIM) {
            #pragma unroll
            for (int r = 0; r < 16; ++r) {
                const int row = rbase + (r & 3) + 8 * (r >> 2);
                const float vv = acc0[r];
                pref[(size_t)row * N_DIM + col] = vv;
                ss = fmaf(vv, vv, ss);
            }
        }
    }
    {
        const int col = bi0 + 64 * wc + 32 + lr;
        if (col < N_DIM) {
            #pragma unroll
            for (int r = 0; r < 16; ++r) {
                const int row = rbase + (r & 3) + 8 * (r >> 2);
                const float vv = acc1[r];
                pref[(size_t)row * N_DIM + col] = vv;
                ss = fmaf(vv, vv, ss);
            }
        }
    }

    #pragma unroll
    for (int off = 32; off > 0; off >>= 1) ss += __shfl_xor(ss, off, 64);
    if (lane == 0) red[wid] = ss;
    __syncthreads();
    if (tid == 0)
        atomicAdd(out, red[0] + red[1] + red[2] + red[3]);
}

// Positive-term correction: loss += sum over UNIQUE seq entries of (1 - 2s).
// One wave per batch row; K=64 == wave size: lane k holds dim k.
__global__ __launch_bounds__(64) void pos_kernel(
    const float* __restrict__ user_emb, const float* __restrict__ item_emb,
    const int* __restrict__ center_uid, const int* __restrict__ seq,
    float* __restrict__ out)
{
    const int b = blockIdx.x;
    const int lane = threadIdx.x;
    const int sv = (lane < HIST) ? seq[b * HIST + lane] : -1;
    const int uid = center_uid[b];
    const float selv = user_emb[(size_t)uid * K_DIM + lane];
    float corr = 0.f;
    for (int h = 0; h < HIST; ++h) {
        const int i = __shfl(sv, h, 64);
        const unsigned long long dup = __ballot(lane < h && sv == i);
        if (dup == 0ull) {  // first occurrence only (mask sets once)
            float p = selv * item_emb[(size_t)i * K_DIM + lane];
            #pragma unroll
            for (int off = 32; off > 0; off >>= 1) p += __shfl_xor(p, off, 64);
            if (lane == 0) corr += 1.f - 2.f * p;
        }
    }
    if (lane == 0) atomicAdd(out, corr);
}

extern "C" void kernel_launch(void* const* d_in, const int* in_sizes, int n_in,
                              void* d_out, int out_size, void* d_ws, size_t ws_size,
                              hipStream_t stream) {
    const float* user_emb   = (const float*)d_in[0];
    const float* item_emb   = (const float*)d_in[1];
    const int*   center_uid = (const int*)d_in[2];
    const int*   seq        = (const int*)d_in[3];
    float* out = (float*)d_out;

    // out[0] accumulates loss via atomics; pref fully overwritten by GEMM.
    hipMemsetAsync(out, 0, sizeof(float), stream);
    pos_kernel<<<dim3(M_DIM), dim3(64), 0, stream>>>(
        user_emb, item_emb, center_uid, seq, out);
    gemm_loss_kernel<<<dim3(NWG), dim3(256), 0, stream>>>(
        user_emb, item_emb, center_uid, out);
}